// Round 3
// baseline (571.147 us; speedup 1.0000x reference)
//
#include <hip/hip_runtime.h>

typedef __attribute__((ext_vector_type(8))) short s16x8;
typedef __attribute__((ext_vector_type(4))) float f32x4;
typedef __attribute__((ext_vector_type(16))) float f32x16;
typedef __attribute__((ext_vector_type(4))) uint u32x4;

#define MFMA16(a, b, c) __builtin_amdgcn_mfma_f32_16x16x32_bf16((a), (b), (c), 0, 0, 0)
#define MFMA32(a, b, c) __builtin_amdgcn_mfma_f32_32x32x16_bf16((a), (b), (c), 0, 0, 0)

__device__ __forceinline__ ushort f2bf(float f) {
  uint u = __builtin_bit_cast(uint, f);
  u = (u + 0x7fffu + ((u >> 16) & 1u)) >> 16;
  return (ushort)u;
}

// ---------------- weight fp32 -> bf16 ----------------
__global__ __launch_bounds__(256) void cvt_w_kernel(
    const float* __restrict__ s0, const float* __restrict__ s1,
    const float* __restrict__ s2, const float* __restrict__ s3,
    ushort* __restrict__ d0, ushort* __restrict__ d1,
    ushort* __restrict__ d2, ushort* __restrict__ d3) {
  int i = blockIdx.x * 256 + threadIdx.x;  // [0, 16384) float4 over 65536 elems
  const float4* s[4] = {(const float4*)s0, (const float4*)s1, (const float4*)s2, (const float4*)s3};
  ushort* d[4] = {d0, d1, d2, d3};
#pragma unroll
  for (int m = 0; m < 4; ++m) {
    float4 v = s[m][i];
    uint lo = (uint)f2bf(v.x) | ((uint)f2bf(v.y) << 16);
    uint hi = (uint)f2bf(v.z) | ((uint)f2bf(v.w) << 16);
    *(uint2*)(d[m] + (size_t)i * 4) = make_uint2(lo, hi);
  }
}

// ---------------- GroupNorm stats -> per-channel scale/shift ----------------
__global__ __launch_bounds__(256) void gn_stats_kernel(
    const float* __restrict__ x, const float* __restrict__ gw,
    const float* __restrict__ gb, float* __restrict__ scaleB,
    float* __restrict__ shiftB) {
  int b = blockIdx.x >> 3, g = blockIdx.x & 7;
  const float4* src = (const float4*)(x + ((size_t)b * 256 + g * 32) * 4096);
  float s = 0.f, ss = 0.f;
  for (int i = threadIdx.x; i < 32768; i += 256) {
    float4 v = src[i];
    s += v.x + v.y + v.z + v.w;
    ss += v.x * v.x + v.y * v.y + v.z * v.z + v.w * v.w;
  }
#pragma unroll
  for (int off = 32; off; off >>= 1) {
    s += __shfl_down(s, off);
    ss += __shfl_down(ss, off);
  }
  __shared__ float ps[4], pss[4];
  __shared__ float smu, srs;
  int w = threadIdx.x >> 6, lane = threadIdx.x & 63;
  if (lane == 0) { ps[w] = s; pss[w] = ss; }
  __syncthreads();
  if (threadIdx.x == 0) {
    float S = ps[0] + ps[1] + ps[2] + ps[3];
    float SS = pss[0] + pss[1] + pss[2] + pss[3];
    float mu = S * (1.f / 131072.f);
    float var = SS * (1.f / 131072.f) - mu * mu;
    smu = mu;
    srs = rsqrtf(var + 1e-5f);
  }
  __syncthreads();
  if (threadIdx.x < 32) {
    int ch = g * 32 + threadIdx.x;
    float sc = gw[ch] * srs;
    scaleB[b * 256 + ch] = sc;
    shiftB[b * 256 + ch] = gb[ch] - smu * sc;
  }
}

// ---------------- GN apply + transpose: x[b][c][n] -> y[b][n][c] bf16 ----------------
__global__ __launch_bounds__(256) void gn_apply_kernel(
    const float* __restrict__ x, const float* __restrict__ scaleB,
    const float* __restrict__ shiftB, ushort* __restrict__ y) {
  int bid = blockIdx.x;
  int b = bid >> 8;
  int rem = bid & 255;
  int ct = rem >> 6, nt = rem & 63;  // 64-channel x 64-n tile
  int t = threadIdx.x;
  __shared__ float xs[64][65];
  const float* xb = x + ((size_t)b * 256 + ct * 64) * 4096 + nt * 64;
  {
    int r = t >> 2, q = t & 3;
    const float4* src = (const float4*)(xb + (size_t)r * 4096 + q * 16);
#pragma unroll
    for (int i = 0; i < 4; ++i) {
      float4 v = src[i];
      xs[r][q * 16 + i * 4 + 0] = v.x;
      xs[r][q * 16 + i * 4 + 1] = v.y;
      xs[r][q * 16 + i * 4 + 2] = v.z;
      xs[r][q * 16 + i * 4 + 3] = v.w;
    }
  }
  __syncthreads();
  {
    int nr = t >> 2, q = t & 3;
    int c0 = q * 16;
    ushort tmp[16];
#pragma unroll
    for (int i = 0; i < 16; ++i) {
      int ch = ct * 64 + c0 + i;
      float v = xs[c0 + i][nr] * scaleB[b * 256 + ch] + shiftB[b * 256 + ch];
      tmp[i] = f2bf(v);
    }
    ushort* dst = y + ((size_t)b * 4096 + nt * 64 + nr) * 256 + ct * 64 + c0;
    uint p[8];
#pragma unroll
    for (int j = 0; j < 8; ++j) p[j] = (uint)tmp[2 * j] | ((uint)tmp[2 * j + 1] << 16);
    *(uint4*)dst = make_uint4(p[0], p[1], p[2], p[3]);
    *((uint4*)dst + 1) = make_uint4(p[4], p[5], p[6], p[7]);
  }
}

// ---------------- GEMM: C[M][N] = A[M][256] . B[N][256]^T (+bias, +resid) ----------------
// MODE 0: bf16 out, bias over col (N). MODE 1: bf16 out, bias over row (M).
// MODE 2: f32 out, bias over row + residual add.
template <int MODE>
__global__ __launch_bounds__(256) void gemm_bt(
    const ushort* __restrict__ A, const ushort* __restrict__ B,
    size_t aB, size_t bB, int M, int N,
    const float* __restrict__ bias, const float* __restrict__ resid,
    size_t rB, void* __restrict__ Cout, size_t cB) {
  int mTiles = M >> 7;
  int tm = blockIdx.x % mTiles, tn = blockIdx.x / mTiles;
  const ushort* Ab = A + blockIdx.y * aB + (size_t)tm * 128 * 256;
  const ushort* Bb = B + blockIdx.y * bB + (size_t)tn * 128 * 256;

  __shared__ ushort As[128 * 72];
  __shared__ ushort Bs[128 * 72];

  int t = threadIdx.x, lane = t & 63, w = t >> 6;
  int wr = w >> 1, wc = w & 1, lq = lane & 15, lg = lane >> 4;

  f32x4 acc[4][4];
#pragma unroll
  for (int i = 0; i < 4; ++i)
#pragma unroll
    for (int j = 0; j < 4; ++j) acc[i][j] = f32x4{0.f, 0.f, 0.f, 0.f};

  int srow = t >> 1, shalf = t & 1;
#pragma unroll 1
  for (int kb = 0; kb < 4; ++kb) {
    __syncthreads();
    {
      const ushort* sa = Ab + (size_t)srow * 256 + kb * 64 + shalf * 32;
      const ushort* sb = Bb + (size_t)srow * 256 + kb * 64 + shalf * 32;
      ushort* da = &As[srow * 72 + shalf * 32];
      ushort* db = &Bs[srow * 72 + shalf * 32];
#pragma unroll
      for (int j = 0; j < 4; ++j) {
        *(uint4*)(da + j * 8) = *(const uint4*)(sa + j * 8);
        *(uint4*)(db + j * 8) = *(const uint4*)(sb + j * 8);
      }
    }
    __syncthreads();
#pragma unroll
    for (int ks = 0; ks < 2; ++ks) {
      s16x8 af[4], bf[4];
#pragma unroll
      for (int mt = 0; mt < 4; ++mt)
        af[mt] = *(const s16x8*)&As[(wr * 64 + mt * 16 + lq) * 72 + ks * 32 + lg * 8];
#pragma unroll
      for (int nt = 0; nt < 4; ++nt)
        bf[nt] = *(const s16x8*)&Bs[(wc * 64 + nt * 16 + lq) * 72 + ks * 32 + lg * 8];
#pragma unroll
      for (int mt = 0; mt < 4; ++mt)
#pragma unroll
        for (int nt = 0; nt < 4; ++nt)
          acc[mt][nt] = MFMA16(af[mt], bf[nt], acc[mt][nt]);
    }
  }

  int mBase = tm * 128 + wr * 64;
  int nBase = tn * 128 + wc * 64;
#pragma unroll
  for (int mt = 0; mt < 4; ++mt) {
#pragma unroll
    for (int nt = 0; nt < 4; ++nt) {
#pragma unroll
      for (int r = 0; r < 4; ++r) {
        int row = mBase + mt * 16 + lg * 4 + r;
        int col = nBase + nt * 16 + lq;
        size_t idx = (size_t)row * N + col;
        float v = acc[mt][nt][r];
        if (MODE == 0) v += bias[col];
        else v += bias[row];
        if (MODE == 2) {
          float* C = (float*)Cout + blockIdx.y * cB;
          C[idx] = v + resid[blockIdx.y * rB + idx];
        } else {
          ushort* C = (ushort*)Cout + blockIdx.y * cB;
          C[idx] = f2bf(v);
        }
      }
    }
  }
}

// ---------------- Flash attention, zero-LDS main loop ----------------
// q[b][n][256], k[b][n][256], vT[b][256][n] -> o[b][n][256], all bf16.
// Block: 4 waves = 2 q-groups x 2 kv-halves; 64 q rows/block; grid 512.
// Swapped QK^T (A=K,B=Q) at 32x32x16: S^T[kseq][q], q = lane&31.
// In-register softmax; P->PV B-frag via cvt_pk_bf16 + permlane32_swap (T12).
// V^T rows are n-contiguous => PV A-frags load straight from global (L1/L2).
__global__ __launch_bounds__(256, 2) void attn2_kernel(
    const ushort* __restrict__ q, const ushort* __restrict__ k,
    const ushort* __restrict__ vT, ushort* __restrict__ o) {
  const int bb = blockIdx.x & 7;          // batch -> XCD pinning (K+V 4MB in L2)
  const int qt = blockIdx.x >> 3;         // 0..63, 64 q rows each
  const int t = threadIdx.x, w = t >> 6, lane = t & 63;
  const int qg = w >> 1, half = w & 1;
  const int lq = lane & 31, lh = lane >> 5;

  __shared__ ushort xch[2][256 * 34];     // per-qg exchange / transpose buffer
  __shared__ float mlx[2][2][32];

  const int qrow = bb * 4096 + qt * 64 + qg * 32 + lq;
  s16x8 qf[16];
  {
    const ushort* qp = q + (size_t)qrow * 256 + lh * 8;
#pragma unroll
    for (int ct = 0; ct < 16; ++ct) qf[ct] = *(const s16x8*)(qp + ct * 16);
  }
  f32x16 oacc[8];
#pragma unroll
  for (int i = 0; i < 8; ++i) oacc[i] = (f32x16)(0.f);
  float mrun = -3e38f, lrun = 0.f;

  const ushort* kb = k + (size_t)bb * (4096 * 256);
  const ushort* vb = vT + (size_t)bb * (4096 * 256);
  const int kv0 = half * 64;

#pragma unroll 1
  for (int it = 0; it < 64; ++it) {
    const int kv = kv0 + it;
    // ---- QK^T: 16 MFMAs, A-frags straight from global K ----
    const ushort* kp = kb + (size_t)(kv * 32 + lq) * 256 + lh * 8;
    f32x16 s = (f32x16)(0.f);
#pragma unroll
    for (int ct = 0; ct < 16; ++ct) {
      s16x8 kf = *(const s16x8*)(kp + ct * 16);
      s = MFMA32(kf, qf[ct], s);
    }
    // ---- in-register online softmax (q = lane&31; row split across lane^32) ----
    float sv[16];
#pragma unroll
    for (int r = 0; r < 16; ++r) sv[r] = s[r] * 0.0625f;
    float pmax = sv[0];
#pragma unroll
    for (int r = 1; r < 16; ++r) pmax = fmaxf(pmax, sv[r]);
    pmax = fmaxf(pmax, __shfl_xor(pmax, 32));
    if (!__all(pmax - mrun <= 8.f)) {   // defer-max (T13)
      float mnew = fmaxf(mrun, pmax);
      float alpha = __expf(mrun - mnew);
#pragma unroll
      for (int i = 0; i < 8; ++i) oacc[i] *= alpha;
      lrun *= alpha;
      mrun = mnew;
    }
    float p[16], psum = 0.f;
#pragma unroll
    for (int r = 0; r < 16; ++r) {
      p[r] = __expf(sv[r] - mrun);
      psum += p[r];
    }
    psum += __shfl_xor(psum, 32);
    lrun += psum;
    // ---- P -> PV B-frags: 8 cvt_pk + 4 permlane32_swap (T12) ----
    uint c00, c01, c10, c11, c20, c21, c30, c31;
    asm("v_cvt_pk_bf16_f32 %0, %1, %2" : "=v"(c00) : "v"(p[0]),  "v"(p[1]));
    asm("v_cvt_pk_bf16_f32 %0, %1, %2" : "=v"(c01) : "v"(p[2]),  "v"(p[3]));
    asm("v_cvt_pk_bf16_f32 %0, %1, %2" : "=v"(c10) : "v"(p[4]),  "v"(p[5]));
    asm("v_cvt_pk_bf16_f32 %0, %1, %2" : "=v"(c11) : "v"(p[6]),  "v"(p[7]));
    asm("v_cvt_pk_bf16_f32 %0, %1, %2" : "=v"(c20) : "v"(p[8]),  "v"(p[9]));
    asm("v_cvt_pk_bf16_f32 %0, %1, %2" : "=v"(c21) : "v"(p[10]), "v"(p[11]));
    asm("v_cvt_pk_bf16_f32 %0, %1, %2" : "=v"(c30) : "v"(p[12]), "v"(p[13]));
    asm("v_cvt_pk_bf16_f32 %0, %1, %2" : "=v"(c31) : "v"(p[14]), "v"(p[15]));
    asm("v_permlane32_swap_b32 %0, %1" : "+v"(c00), "+v"(c10));
    asm("v_permlane32_swap_b32 %0, %1" : "+v"(c01), "+v"(c11));
    asm("v_permlane32_swap_b32 %0, %1" : "+v"(c20), "+v"(c30));
    asm("v_permlane32_swap_b32 %0, %1" : "+v"(c21), "+v"(c31));
    u32x4 t0 = {c00, c01, c10, c11};   // kseq 0..15 slots
    u32x4 t1 = {c20, c21, c30, c31};   // kseq 16..31 slots
    s16x8 pf0 = __builtin_bit_cast(s16x8, t0);
    s16x8 pf1 = __builtin_bit_cast(s16x8, t1);
    // ---- PV: O^T += V^T . P, A-frags straight from global vT ----
    const ushort* vp = vb + (size_t)lq * 4096 + kv * 32 + lh * 8;
#pragma unroll
    for (int db = 0; db < 8; ++db) {
      s16x8 vf0 = *(const s16x8*)(vp + (size_t)db * 32 * 4096);
      s16x8 vf1 = *(const s16x8*)(vp + (size_t)db * 32 * 4096 + 16);
      oacc[db] = MFMA32(vf0, pf0, oacc[db]);
      oacc[db] = MFMA32(vf1, pf1, oacc[db]);
    }
  }

  // ---- epilogue: combine kv-halves in LDS, transpose, coalesced store ----
  if (half == 1) {
#pragma unroll
    for (int db = 0; db < 8; ++db)
#pragma unroll
      for (int r = 0; r < 16; ++r) {
        int d = db * 32 + (r & 3) + 8 * (r >> 2) + 4 * lh;
        xch[qg][d * 34 + lq] = f2bf(oacc[db][r]);
      }
    if (lh == 0) { mlx[qg][0][lq] = mrun; mlx[qg][1][lq] = lrun; }
  }
  __syncthreads();
  if (half == 0) {
    float m1 = mlx[qg][0][lq], l1 = mlx[qg][1][lq];
    float M = fmaxf(mrun, m1);
    float e0 = __expf(mrun - M);
    float e1 = __expf(m1 - M);
    float inv = 1.f / (lrun * e0 + l1 * e1);
#pragma unroll
    for (int db = 0; db < 8; ++db)
#pragma unroll
      for (int r = 0; r < 16; ++r) {
        int d = db * 32 + (r & 3) + 8 * (r >> 2) + 4 * lh;
        uint raw = (uint)xch[qg][d * 34 + lq] << 16;
        float o1 = __builtin_bit_cast(float, raw);
        oacc[db][r] = (oacc[db][r] * e0 + o1 * e1) * inv;
      }
  }
  __syncthreads();
  if (half == 0) {
    ushort* ob = &xch[qg][0];
#pragma unroll
    for (int db = 0; db < 8; ++db)
#pragma unroll
      for (int rp = 0; rp < 8; ++rp) {
        int r0 = rp * 2;
        int d0 = db * 32 + (r0 & 3) + 8 * (r0 >> 2) + 4 * lh;
        uint pk;
        asm("v_cvt_pk_bf16_f32 %0, %1, %2"
            : "=v"(pk) : "v"(oacc[db][r0]), "v"(oacc[db][r0 + 1]));
        *(uint*)&ob[lq * 272 + d0] = pk;
      }
  }
  __syncthreads();
  {
    int i = t & 127, qg2 = t >> 7;
    int qq = i >> 2, ch = i & 3;
    const ushort* src = &xch[qg2][qq * 272 + ch * 64];
    ushort* dst = o + ((size_t)(bb * 4096 + qt * 64 + qg2 * 32 + qq)) * 256 + ch * 64;
#pragma unroll
    for (int j = 0; j < 8; ++j)
      *(((uint4*)dst) + j) = *(((const uint4*)src) + j);
  }
}

extern "C" void kernel_launch(void* const* d_in, const int* in_sizes, int n_in,
                              void* d_out, int out_size, void* d_ws, size_t ws_size,
                              hipStream_t stream) {
  const float* x   = (const float*)d_in[0];
  const float* gnw = (const float*)d_in[1];
  const float* gnb = (const float*)d_in[2];
  const float* wq  = (const float*)d_in[3];
  const float* bq  = (const float*)d_in[4];
  const float* wk  = (const float*)d_in[5];
  const float* bk  = (const float*)d_in[6];
  const float* wv  = (const float*)d_in[7];
  const float* bv  = (const float*)d_in[8];
  const float* wp  = (const float*)d_in[9];
  const float* bp  = (const float*)d_in[10];

  const size_t SEQ = 4096, CH = 256;
  const size_t MAT = SEQ * CH;           // elements per [n][c] matrix per batch
  char* ws = (char*)d_ws;
  // each big buffer = 8 * 4096 * 256 * 2 bytes = 16 MiB
  const size_t BUF = 8 * MAT * 2;
  ushort* y    = (ushort*)(ws + 0 * BUF);
  ushort* qb   = (ushort*)(ws + 1 * BUF);
  ushort* kb_  = (ushort*)(ws + 2 * BUF);
  ushort* vtb  = (ushort*)(ws + 3 * BUF);
  ushort* oab  = y;  // y is dead after the V GEMM; reuse for attention output
  ushort* wqb  = (ushort*)(ws + 4 * BUF);
  ushort* wkb  = wqb + 65536;
  ushort* wvb  = wkb + 65536;
  ushort* wpb  = wvb + 65536;
  float* scaleB = (float*)(wpb + 65536);
  float* shiftB = scaleB + 8 * 256;

  cvt_w_kernel<<<64, 256, 0, stream>>>(wq, wk, wv, wp, wqb, wkb, wvb, wpb);
  gn_stats_kernel<<<64, 256, 0, stream>>>(x, gnw, gnb, scaleB, shiftB);
  gn_apply_kernel<<<2048, 256, 0, stream>>>(x, scaleB, shiftB, y);

  // q[n][o] = y . wq^T + bq(col)
  gemm_bt<0><<<dim3(64, 8), 256, 0, stream>>>(y, wqb, MAT, 0, 4096, 256, bq,
                                              nullptr, 0, qb, MAT);
  // k'[m][o] = y . wk^T + bk(col)
  gemm_bt<0><<<dim3(64, 8), 256, 0, stream>>>(y, wkb, MAT, 0, 4096, 256, bk,
                                              nullptr, 0, kb_, MAT);
  // vT[o][m] = wv . y^T + bv(row)
  gemm_bt<1><<<dim3(64, 8), 256, 0, stream>>>(wvb, y, 0, MAT, 256, 4096, bv,
                                              nullptr, 0, vtb, MAT);

  attn2_kernel<<<512, 256, 0, stream>>>(qb, kb_, vtb, oab);

  // out[co][n] = wp . oattn^T + bp(row) + x   (f32)
  gemm_bt<2><<<dim3(64, 8), 256, 0, stream>>>(wpb, oab, 0, MAT, 256, 4096, bp,
                                              x, MAT, d_out, MAT);
}

// Round 4
// 324.149 us; speedup vs baseline: 1.7620x; 1.7620x over previous
//
#include <hip/hip_runtime.h>

typedef __attribute__((ext_vector_type(8))) short s16x8;
typedef __attribute__((ext_vector_type(4))) float f32x4;
typedef __attribute__((ext_vector_type(16))) float f32x16;
typedef __attribute__((ext_vector_type(4))) uint u32x4;

#define MFMA16(a, b, c) __builtin_amdgcn_mfma_f32_16x16x32_bf16((a), (b), (c), 0, 0, 0)
#define MFMA32(a, b, c) __builtin_amdgcn_mfma_f32_32x32x16_bf16((a), (b), (c), 0, 0, 0)

__device__ __forceinline__ ushort f2bf(float f) {
  uint u = __builtin_bit_cast(uint, f);
  u = (u + 0x7fffu + ((u >> 16) & 1u)) >> 16;
  return (ushort)u;
}

// ---------------- weight fp32 -> bf16 ----------------
__global__ __launch_bounds__(256) void cvt_w_kernel(
    const float* __restrict__ s0, const float* __restrict__ s1,
    const float* __restrict__ s2, const float* __restrict__ s3,
    ushort* __restrict__ d0, ushort* __restrict__ d1,
    ushort* __restrict__ d2, ushort* __restrict__ d3) {
  int i = blockIdx.x * 256 + threadIdx.x;  // [0, 16384) float4 over 65536 elems
  const float4* s[4] = {(const float4*)s0, (const float4*)s1, (const float4*)s2, (const float4*)s3};
  ushort* d[4] = {d0, d1, d2, d3};
#pragma unroll
  for (int m = 0; m < 4; ++m) {
    float4 v = s[m][i];
    uint lo = (uint)f2bf(v.x) | ((uint)f2bf(v.y) << 16);
    uint hi = (uint)f2bf(v.z) | ((uint)f2bf(v.w) << 16);
    *(uint2*)(d[m] + (size_t)i * 4) = make_uint2(lo, hi);
  }
}

// ---------------- GroupNorm stats -> per-channel scale/shift ----------------
__global__ __launch_bounds__(256) void gn_stats_kernel(
    const float* __restrict__ x, const float* __restrict__ gw,
    const float* __restrict__ gb, float* __restrict__ scaleB,
    float* __restrict__ shiftB) {
  int b = blockIdx.x >> 3, g = blockIdx.x & 7;
  const float4* src = (const float4*)(x + ((size_t)b * 256 + g * 32) * 4096);
  float s = 0.f, ss = 0.f;
  for (int i = threadIdx.x; i < 32768; i += 256) {
    float4 v = src[i];
    s += v.x + v.y + v.z + v.w;
    ss += v.x * v.x + v.y * v.y + v.z * v.z + v.w * v.w;
  }
#pragma unroll
  for (int off = 32; off; off >>= 1) {
    s += __shfl_down(s, off);
    ss += __shfl_down(ss, off);
  }
  __shared__ float ps[4], pss[4];
  __shared__ float smu, srs;
  int w = threadIdx.x >> 6, lane = threadIdx.x & 63;
  if (lane == 0) { ps[w] = s; pss[w] = ss; }
  __syncthreads();
  if (threadIdx.x == 0) {
    float S = ps[0] + ps[1] + ps[2] + ps[3];
    float SS = pss[0] + pss[1] + pss[2] + pss[3];
    float mu = S * (1.f / 131072.f);
    float var = SS * (1.f / 131072.f) - mu * mu;
    smu = mu;
    srs = rsqrtf(var + 1e-5f);
  }
  __syncthreads();
  if (threadIdx.x < 32) {
    int ch = g * 32 + threadIdx.x;
    float sc = gw[ch] * srs;
    scaleB[b * 256 + ch] = sc;
    shiftB[b * 256 + ch] = gb[ch] - smu * sc;
  }
}

// ---------------- GN apply + transpose: x[b][c][n] -> y[b][n][c] bf16 ----------------
__global__ __launch_bounds__(256) void gn_apply_kernel(
    const float* __restrict__ x, const float* __restrict__ scaleB,
    const float* __restrict__ shiftB, ushort* __restrict__ y) {
  int bid = blockIdx.x;
  int b = bid >> 8;
  int rem = bid & 255;
  int ct = rem >> 6, nt = rem & 63;  // 64-channel x 64-n tile
  int t = threadIdx.x;
  __shared__ float xs[64][65];
  const float* xb = x + ((size_t)b * 256 + ct * 64) * 4096 + nt * 64;
  {
    int r = t >> 2, q = t & 3;
    const float4* src = (const float4*)(xb + (size_t)r * 4096 + q * 16);
#pragma unroll
    for (int i = 0; i < 4; ++i) {
      float4 v = src[i];
      xs[r][q * 16 + i * 4 + 0] = v.x;
      xs[r][q * 16 + i * 4 + 1] = v.y;
      xs[r][q * 16 + i * 4 + 2] = v.z;
      xs[r][q * 16 + i * 4 + 3] = v.w;
    }
  }
  __syncthreads();
  {
    int nr = t >> 2, q = t & 3;
    int c0 = q * 16;
    ushort tmp[16];
#pragma unroll
    for (int i = 0; i < 16; ++i) {
      int ch = ct * 64 + c0 + i;
      float v = xs[c0 + i][nr] * scaleB[b * 256 + ch] + shiftB[b * 256 + ch];
      tmp[i] = f2bf(v);
    }
    ushort* dst = y + ((size_t)b * 4096 + nt * 64 + nr) * 256 + ct * 64 + c0;
    uint p[8];
#pragma unroll
    for (int j = 0; j < 8; ++j) p[j] = (uint)tmp[2 * j] | ((uint)tmp[2 * j + 1] << 16);
    *(uint4*)dst = make_uint4(p[0], p[1], p[2], p[3]);
    *((uint4*)dst + 1) = make_uint4(p[4], p[5], p[6], p[7]);
  }
}

// ---------------- GEMM: C[M][N] = A[M][256] . B[N][256]^T (+bias, +resid) ----------------
template <int MODE>
__global__ __launch_bounds__(256) void gemm_bt(
    const ushort* __restrict__ A, const ushort* __restrict__ B,
    size_t aB, size_t bB, int M, int N,
    const float* __restrict__ bias, const float* __restrict__ resid,
    size_t rB, void* __restrict__ Cout, size_t cB) {
  int mTiles = M >> 7;
  int tm = blockIdx.x % mTiles, tn = blockIdx.x / mTiles;
  const ushort* Ab = A + blockIdx.y * aB + (size_t)tm * 128 * 256;
  const ushort* Bb = B + blockIdx.y * bB + (size_t)tn * 128 * 256;

  __shared__ ushort As[128 * 72];
  __shared__ ushort Bs[128 * 72];

  int t = threadIdx.x, lane = t & 63, w = t >> 6;
  int wr = w >> 1, wc = w & 1, lq = lane & 15, lg = lane >> 4;

  f32x4 acc[4][4];
#pragma unroll
  for (int i = 0; i < 4; ++i)
#pragma unroll
    for (int j = 0; j < 4; ++j) acc[i][j] = f32x4{0.f, 0.f, 0.f, 0.f};

  int srow = t >> 1, shalf = t & 1;
#pragma unroll 1
  for (int kb = 0; kb < 4; ++kb) {
    __syncthreads();
    {
      const ushort* sa = Ab + (size_t)srow * 256 + kb * 64 + shalf * 32;
      const ushort* sb = Bb + (size_t)srow * 256 + kb * 64 + shalf * 32;
      ushort* da = &As[srow * 72 + shalf * 32];
      ushort* db = &Bs[srow * 72 + shalf * 32];
#pragma unroll
      for (int j = 0; j < 4; ++j) {
        *(uint4*)(da + j * 8) = *(const uint4*)(sa + j * 8);
        *(uint4*)(db + j * 8) = *(const uint4*)(sb + j * 8);
      }
    }
    __syncthreads();
#pragma unroll
    for (int ks = 0; ks < 2; ++ks) {
      s16x8 af[4], bf[4];
#pragma unroll
      for (int mt = 0; mt < 4; ++mt)
        af[mt] = *(const s16x8*)&As[(wr * 64 + mt * 16 + lq) * 72 + ks * 32 + lg * 8];
#pragma unroll
      for (int nt = 0; nt < 4; ++nt)
        bf[nt] = *(const s16x8*)&Bs[(wc * 64 + nt * 16 + lq) * 72 + ks * 32 + lg * 8];
#pragma unroll
      for (int mt = 0; mt < 4; ++mt)
#pragma unroll
        for (int nt = 0; nt < 4; ++nt)
          acc[mt][nt] = MFMA16(af[mt], bf[nt], acc[mt][nt]);
    }
  }

  int mBase = tm * 128 + wr * 64;
  int nBase = tn * 128 + wc * 64;
#pragma unroll
  for (int mt = 0; mt < 4; ++mt) {
#pragma unroll
    for (int nt = 0; nt < 4; ++nt) {
#pragma unroll
      for (int r = 0; r < 4; ++r) {
        int row = mBase + mt * 16 + lg * 4 + r;
        int col = nBase + nt * 16 + lq;
        size_t idx = (size_t)row * N + col;
        float v = acc[mt][nt][r];
        if (MODE == 0) v += bias[col];
        else v += bias[row];
        if (MODE == 2) {
          float* C = (float*)Cout + blockIdx.y * cB;
          C[idx] = v + resid[blockIdx.y * rB + idx];
        } else {
          ushort* C = (ushort*)Cout + blockIdx.y * cB;
          C[idx] = f2bf(v);
        }
      }
    }
  }
}

// ---------------- Flash attention v3: LDS-staged, dbuf + counted vmcnt ----------------
// Grid 256 (= 8 batch x 32 qtiles), 4 waves x 32 q-rows = 128 q-rows/block.
// All waves share one 32-row KV chunk staged via global_load_lds (swizzled src).
// Swapped QK^T 32x32x16 (S^T, q = lane&31), in-reg softmax, T12 P->B-frag.
__global__ __launch_bounds__(256, 1) void attn3_kernel(
    const ushort* __restrict__ q, const ushort* __restrict__ k,
    const ushort* __restrict__ vT, ushort* __restrict__ o) {
  const int bb = blockIdx.x & 7;          // batch -> XCD pinning
  const int qt = blockIdx.x >> 3;         // 0..31, 128 q rows each
  const int t = threadIdx.x, w = t >> 6, lane = t & 63;
  const int lq = lane & 31, lh = lane >> 5;

  __shared__ ushort L[2][16384];          // per buf: K [0,8192), V [8192,16384)

  const ushort* kb = k + (size_t)bb * (4096 * 256);
  const ushort* vb = vT + (size_t)bb * (4096 * 256);

  // Q fragments (loop-invariant)
  const int qrow = bb * 4096 + qt * 128 + w * 32 + lq;
  s16x8 qf[16];
  {
    const ushort* qp = q + (size_t)qrow * 256 + lh * 8;
#pragma unroll
    for (int ct = 0; ct < 16; ++ct) qf[ct] = *(const s16x8*)(qp + ct * 16);
  }
  f32x16 oacc[8];
#pragma unroll
  for (int i = 0; i < 8; ++i) oacc[i] = (f32x16)(0.f);
  float mrun = -3e38f, lrun = 0.f;

  // ---- staging lambda: 8 global_load_lds (4 K + 4 V), pre-swizzled sources ----
  auto stage = [&](int chunk, int buf) {
    const ushort* kcb = kb + (size_t)chunk * (32 * 256);
    const ushort* vcb = vb + (size_t)chunk * 32;
    ushort* Kd = &L[buf][0];
    ushort* Vd = &L[buf][8192];
#pragma unroll
    for (int i = 0; i < 4; ++i) {
      int Lu = (w * 4 + i) * 64 + lane;
      // K: LDS(row, c) holds global K(row, c ^ (row&7)); row-major 512B rows
      int row = Lu >> 5, c = Lu & 31;
      const ushort* ksrc = kcb + row * 256 + ((c ^ (row & 7)) << 3);
      __builtin_amdgcn_global_load_lds(
          (const __attribute__((address_space(1))) uint*)ksrc,
          (__attribute__((address_space(3))) uint*)(Kd + (w * 4 + i) * 512), 16, 0, 0);
      // V: row-pair 128B blocks, slot8(row,u) = ((row&1)*4+u) ^ ((row>>1)&7)
      int rp = Lu >> 3, s8 = Lu & 7;
      int x = s8 ^ (rp & 7);
      int vrow = rp * 2 + (x >> 2), u = x & 3;
      const ushort* vsrc = vcb + (size_t)vrow * 4096 + u * 8;
      __builtin_amdgcn_global_load_lds(
          (const __attribute__((address_space(1))) uint*)vsrc,
          (__attribute__((address_space(3))) uint*)(Vd + (w * 4 + i) * 512), 16, 0, 0);
    }
  };

  stage(0, 0);

#pragma unroll 1
  for (int it = 0; it < 128; ++it) {
    const int cur = it & 1;
    if (it < 127) {
      stage(it + 1, cur ^ 1);
      asm volatile("s_waitcnt vmcnt(8)" ::: "memory");
    } else {
      asm volatile("s_waitcnt vmcnt(0)" ::: "memory");
    }
    __builtin_amdgcn_s_barrier();

    // ---- QK^T: 16 MFMAs, A-frags from swizzled K LDS ----
    const ushort* Kbf = &L[cur][0];
    f32x16 s = (f32x16)(0.f);
#pragma unroll
    for (int ct = 0; ct < 16; ++ct) {
      int unit = ((ct * 2 + lh) ^ (lq & 7));
      s16x8 kf = *(const s16x8*)(Kbf + lq * 256 + unit * 8);
      s = MFMA32(kf, qf[ct], s);
    }
    // ---- in-register online softmax ----
    float sv[16];
#pragma unroll
    for (int r = 0; r < 16; ++r) sv[r] = s[r] * 0.0625f;
    float pmax = sv[0];
#pragma unroll
    for (int r = 1; r < 16; ++r) pmax = fmaxf(pmax, sv[r]);
    pmax = fmaxf(pmax, __shfl_xor(pmax, 32));
    if (!__all(pmax - mrun <= 8.f)) {   // defer-max (T13)
      float mnew = fmaxf(mrun, pmax);
      float alpha = __expf(mrun - mnew);
#pragma unroll
      for (int i = 0; i < 8; ++i) oacc[i] *= alpha;
      lrun *= alpha;
      mrun = mnew;
    }
    float p[16], psum = 0.f;
#pragma unroll
    for (int r = 0; r < 16; ++r) {
      p[r] = __expf(sv[r] - mrun);
      psum += p[r];
    }
    psum += __shfl_xor(psum, 32);
    lrun += psum;
    // ---- P -> PV B-frags (T12) ----
    uint c00, c01, c10, c11, c20, c21, c30, c31;
    asm("v_cvt_pk_bf16_f32 %0, %1, %2" : "=v"(c00) : "v"(p[0]),  "v"(p[1]));
    asm("v_cvt_pk_bf16_f32 %0, %1, %2" : "=v"(c01) : "v"(p[2]),  "v"(p[3]));
    asm("v_cvt_pk_bf16_f32 %0, %1, %2" : "=v"(c10) : "v"(p[4]),  "v"(p[5]));
    asm("v_cvt_pk_bf16_f32 %0, %1, %2" : "=v"(c11) : "v"(p[6]),  "v"(p[7]));
    asm("v_cvt_pk_bf16_f32 %0, %1, %2" : "=v"(c20) : "v"(p[8]),  "v"(p[9]));
    asm("v_cvt_pk_bf16_f32 %0, %1, %2" : "=v"(c21) : "v"(p[10]), "v"(p[11]));
    asm("v_cvt_pk_bf16_f32 %0, %1, %2" : "=v"(c30) : "v"(p[12]), "v"(p[13]));
    asm("v_cvt_pk_bf16_f32 %0, %1, %2" : "=v"(c31) : "v"(p[14]), "v"(p[15]));
    asm("v_permlane32_swap_b32 %0, %1" : "+v"(c00), "+v"(c10));
    asm("v_permlane32_swap_b32 %0, %1" : "+v"(c01), "+v"(c11));
    asm("v_permlane32_swap_b32 %0, %1" : "+v"(c20), "+v"(c30));
    asm("v_permlane32_swap_b32 %0, %1" : "+v"(c21), "+v"(c31));
    u32x4 t0 = {c00, c01, c10, c11};
    u32x4 t1 = {c20, c21, c30, c31};
    s16x8 pf0 = __builtin_bit_cast(s16x8, t0);
    s16x8 pf1 = __builtin_bit_cast(s16x8, t1);
    // ---- PV: A-frags from swizzled V LDS ----
    const ushort* Vbf = &L[cur][8192];
    const int rp7 = (lq >> 1) & 7;
    const int b4 = (lq & 1) * 4;
#pragma unroll
    for (int db = 0; db < 8; ++db) {
      const ushort* base = Vbf + (db * 16 + (lq >> 1)) * 64;
      int s0 = (b4 + lh) ^ rp7;
      int s1 = (b4 + 2 + lh) ^ rp7;
      s16x8 vf0 = *(const s16x8*)(base + s0 * 8);
      s16x8 vf1 = *(const s16x8*)(base + s1 * 8);
      oacc[db] = MFMA32(vf0, pf0, oacc[db]);
      oacc[db] = MFMA32(vf1, pf1, oacc[db]);
    }
    asm volatile("" ::: "memory");
    __builtin_amdgcn_s_barrier();
    asm volatile("" ::: "memory");
  }

  // ---- epilogue: scale by 1/l, transpose via LDS, coalesced store ----
  float inv = 1.f / lrun;
  ushort* wreg = &L[0][0] + w * 8192;   // 32q x 256d bf16 per wave
#pragma unroll
  for (int db = 0; db < 8; ++db)
#pragma unroll
    for (int rp = 0; rp < 8; ++rp) {
      int r0 = rp * 2;
      int d0 = db * 32 + (r0 & 3) + 8 * (r0 >> 2) + 4 * lh;
      uint pk;
      asm("v_cvt_pk_bf16_f32 %0, %1, %2"
          : "=v"(pk) : "v"(oacc[db][r0] * inv), "v"(oacc[db][r0 + 1] * inv));
      *(uint*)&wreg[lq * 256 + d0] = pk;
    }
  asm volatile("" ::: "memory");
  __builtin_amdgcn_s_barrier();
  asm volatile("" ::: "memory");
  {
    const ushort* srcr = wreg + (lane >> 1) * 256 + (lane & 1) * 128;
    ushort* dstr = o + ((size_t)(bb * 4096 + qt * 128 + w * 32 + (lane >> 1))) * 256 +
                   (lane & 1) * 128;
#pragma unroll
    for (int j = 0; j < 16; ++j)
      ((uint4*)dstr)[j] = ((const uint4*)srcr)[j];
  }
}

extern "C" void kernel_launch(void* const* d_in, const int* in_sizes, int n_in,
                              void* d_out, int out_size, void* d_ws, size_t ws_size,
                              hipStream_t stream) {
  const float* x   = (const float*)d_in[0];
  const float* gnw = (const float*)d_in[1];
  const float* gnb = (const float*)d_in[2];
  const float* wq  = (const float*)d_in[3];
  const float* bq  = (const float*)d_in[4];
  const float* wk  = (const float*)d_in[5];
  const float* bk  = (const float*)d_in[6];
  const float* wv  = (const float*)d_in[7];
  const float* bv  = (const float*)d_in[8];
  const float* wp  = (const float*)d_in[9];
  const float* bp  = (const float*)d_in[10];

  const size_t SEQ = 4096, CH = 256;
  const size_t MAT = SEQ * CH;
  char* ws = (char*)d_ws;
  const size_t BUF = 8 * MAT * 2;        // 16 MiB
  ushort* y    = (ushort*)(ws + 0 * BUF);
  ushort* qb   = (ushort*)(ws + 1 * BUF);
  ushort* kb_  = (ushort*)(ws + 2 * BUF);
  ushort* vtb  = (ushort*)(ws + 3 * BUF);
  ushort* oab  = y;  // y dead after V GEMM
  ushort* wqb  = (ushort*)(ws + 4 * BUF);
  ushort* wkb  = wqb + 65536;
  ushort* wvb  = wkb + 65536;
  ushort* wpb  = wvb + 65536;
  float* scaleB = (float*)(wpb + 65536);
  float* shiftB = scaleB + 8 * 256;

  cvt_w_kernel<<<64, 256, 0, stream>>>(wq, wk, wv, wp, wqb, wkb, wvb, wpb);
  gn_stats_kernel<<<64, 256, 0, stream>>>(x, gnw, gnb, scaleB, shiftB);
  gn_apply_kernel<<<2048, 256, 0, stream>>>(x, scaleB, shiftB, y);

  gemm_bt<0><<<dim3(64, 8), 256, 0, stream>>>(y, wqb, MAT, 0, 4096, 256, bq,
                                              nullptr, 0, qb, MAT);
  gemm_bt<0><<<dim3(64, 8), 256, 0, stream>>>(y, wkb, MAT, 0, 4096, 256, bk,
                                              nullptr, 0, kb_, MAT);
  gemm_bt<1><<<dim3(64, 8), 256, 0, stream>>>(wvb, y, 0, MAT, 256, 4096, bv,
                                              nullptr, 0, vtb, MAT);

  attn3_kernel<<<256, 256, 0, stream>>>(qb, kb_, vtb, oab);

  gemm_bt<2><<<dim3(64, 8), 256, 0, stream>>>(wpb, oab, 0, MAT, 256, 4096, bp,
                                              x, MAT, d_out, MAT);
}